// Round 4
// 432.306 us; speedup vs baseline: 1.0192x; 1.0192x over previous
//
#include <hip/hip_runtime.h>

typedef _Float16 f16;
typedef __attribute__((ext_vector_type(8))) _Float16 f16x8;
typedef __attribute__((ext_vector_type(4))) _Float16 f16x4;
typedef __attribute__((ext_vector_type(4))) float  f32x4;

#define B_    16384
#define N_    32
#define DIN_  128
#define DOUT_ 256

__device__ __forceinline__ float rdlane(float v, int lane) {
    return __uint_as_float(__builtin_amdgcn_readlane(__float_as_uint(v), lane));
}
__device__ __forceinline__ float red32(float v) {   // sum within each 32-lane half
    v += __shfl_xor(v, 1); v += __shfl_xor(v, 2); v += __shfl_xor(v, 4);
    v += __shfl_xor(v, 8); v += __shfl_xor(v, 16);
    return v;
}
// X-plane index in halves: row n (0..31) * stride 272, col o (0..255) XOR-swizzled.
// o ^ ((n&7)<<3) flips only bits 3..5 of o: stays in [0,256), preserves 8-half
// (16B) blocks so ds_read_b128 alignment holds, and is injective per row.
// Rows never overlap (272 > 255 max offset). Write/read both use this function.
__device__ __forceinline__ int xidx(int n, int o) {
    return n * 272 + (o ^ ((n & 7) << 3));
}

// Pack W (DIN x DOUT, fp32) into fp16 B-fragment order for mfma_f32_16x16x32_f16.
// Fragment: lane l holds B[k = ks*32 + (l>>4)*8 + j][o = ot*16 + (l&15)], j=0..7.
__global__ void prep_w(const float* __restrict__ W, f16* __restrict__ wp) {
    int tid = blockIdx.x * 256 + threadIdx.x;   // 0..4095
    int ks = tid >> 10;
    int ot = (tid >> 6) & 15;
    int l  = tid & 63;
    int k0 = ks * 32 + ((l >> 4) << 3);
    int o  = ot * 16 + (l & 15);
    f16 v[8];
#pragma unroll
    for (int j = 0; j < 8; ++j) v[j] = (f16)W[(size_t)(k0 + j) * DOUT_ + o];
    *reinterpret_cast<f16x8*>(&wp[(size_t)tid * 8]) = *reinterpret_cast<f16x8*>(v);
}

// LDS pool layout (bytes):
//   [0, 17408)        phase A: elds (f16, 32 rows x stride 136, 8704 B used)
//                     phase B: xh plane (f16, xidx layout, 32*272*2 = 17408 B)
//   [17408, 34816)    xe plane (f16, xidx layout)
//   [34816, 39440)    glds (f32, 32 rows x stride 36 + 4)
//   [39440, 39572)    cpls[32], scls
#define PLANE_ 17408

__global__ __launch_bounds__(256, 4) void dyr_main(
    const float* __restrict__ embeds, const float* __restrict__ weights,
    const f16* __restrict__ wp,       const float* __restrict__ bias,
    float* __restrict__ out)
{
    __shared__ __align__(16) char pool[39584];
    f16*   elds = reinterpret_cast<f16*>(pool);
    f16*   xh   = reinterpret_cast<f16*>(pool);            // aliases elds (dead after P1)
    f16*   xe   = reinterpret_cast<f16*>(pool + PLANE_);
    float* glds = reinterpret_cast<float*>(pool + 2 * PLANE_);
    float* cpls = reinterpret_cast<float*>(pool + 2 * PLANE_ + 4624);
    float* scls = cpls + 32;

    const int tid = threadIdx.x;
    const int w   = tid >> 6;      // wave 0..3 -> owns output cols [w*64, w*64+64)
    const int l   = tid & 63;
    const int col = l & 15;
    const int q   = l >> 4;        // quad within wave
    const int b   = blockIdx.x;
    const int n0  = l & 31;        // routing row for wave 0

    // issue the routing-logit load early (wave 0 consumes it much later)
    float bval = (w == 0) ? weights[(size_t)b * N_ + n0] : 0.f;

    // ---- P0: stage embeds[b] (32x128 fp32) -> f16 LDS ----
    const float4* e4 = reinterpret_cast<const float4*>(embeds + (size_t)b * N_ * DIN_);
#pragma unroll
    for (int p = 0; p < 4; ++p) {
        int fi = p * 256 + tid;            // float4 index, 32 per row
        float4 v = e4[fi];
        int m = fi >> 5;
        int k = (fi & 31) << 2;
        f16 pk[4] = { (f16)v.x, (f16)v.y, (f16)v.z, (f16)v.w };
        *reinterpret_cast<f16x4*>(&elds[m * 136 + k]) = *reinterpret_cast<f16x4*>(pk);
    }
    __syncthreads();

    // ---- P1: GEMM x[n][o] = sum_k e[n][k]*W[k][o], o in wave's 64 cols ----
    f32x4 acc[2][4];
#pragma unroll
    for (int mt = 0; mt < 2; ++mt)
#pragma unroll
        for (int t = 0; t < 4; ++t) acc[mt][t] = (f32x4){0.f, 0.f, 0.f, 0.f};

    const int aoff0 = col * 136 + (q << 3);   // A-frag: m=col(+16*mt), k=q*8(+32*ks)
#pragma unroll
    for (int ks = 0; ks < 4; ++ks) {
        f16x8 a0 = *reinterpret_cast<const f16x8*>(&elds[aoff0 + ks * 32]);
        f16x8 a1 = *reinterpret_cast<const f16x8*>(&elds[aoff0 + 16 * 136 + ks * 32]);
#pragma unroll
        for (int t = 0; t < 4; ++t) {
            f16x8 bf = *reinterpret_cast<const f16x8*>(
                &wp[((size_t)((ks * 16) + (w * 4 + t)) * 64 + l) * 8]);
            acc[0][t] = __builtin_amdgcn_mfma_f32_16x16x32_f16(a0, bf, acc[0][t], 0, 0, 0);
            acc[1][t] = __builtin_amdgcn_mfma_f32_16x16x32_f16(a1, bf, acc[1][t], 0, 0, 0);
        }
    }
    // C/D layout: value = x[n = mt*16 + q*4 + r][o = w*64 + t*16 + col]
#pragma unroll
    for (int t = 0; t < 4; ++t) {
        float bv = bias[w * 64 + t * 16 + col];
#pragma unroll
        for (int mt = 0; mt < 2; ++mt)
#pragma unroll
            for (int r = 0; r < 4; ++r) acc[mt][t][r] += bv;
    }
    __syncthreads();   // elds reads done everywhere; planes may now overwrite it

    // ---- P2: spill X (un-normalized) as split fp16 (h + e) to LDS ----
#pragma unroll
    for (int mt = 0; mt < 2; ++mt)
#pragma unroll
        for (int t = 0; t < 4; ++t) {
            int o = w * 64 + t * 16 + col;
#pragma unroll
            for (int r = 0; r < 4; ++r) {
                float xv = acc[mt][t][r];
                f16 h = (f16)xv;
                f16 e = (f16)(xv - (float)h);
                int idx = xidx(mt * 16 + q * 4 + r, o);
                xh[idx] = h;
                xe[idx] = e;
            }
        }
    __syncthreads();

    // ---- P3: G = X X^T via split-fp16 MFMA (h*h + h*e + e*h; e*e dropped). ----
    // For X X^T the B-fragment read pattern == A-fragment pattern.
    {
        const int mi = w >> 1, ni = w & 1;
        f32x4 gacc = (f32x4){0.f, 0.f, 0.f, 0.f};
#pragma unroll
        for (int ks = 0; ks < 8; ++ks) {
            int ra = xidx(mi * 16 + col, ks * 32 + (q << 3));
            f16x8 ha = *reinterpret_cast<const f16x8*>(&xh[ra]);
            f16x8 ea = *reinterpret_cast<const f16x8*>(&xe[ra]);
            f16x8 hb = ha, eb = ea;
            if (mi != ni) {
                int rb = xidx(ni * 16 + col, ks * 32 + (q << 3));
                hb = *reinterpret_cast<const f16x8*>(&xh[rb]);
                eb = *reinterpret_cast<const f16x8*>(&xe[rb]);
            }
            gacc = __builtin_amdgcn_mfma_f32_16x16x32_f16(ha, hb, gacc, 0, 0, 0);
            gacc = __builtin_amdgcn_mfma_f32_16x16x32_f16(ha, eb, gacc, 0, 0, 0);
            gacc = __builtin_amdgcn_mfma_f32_16x16x32_f16(ea, hb, gacc, 0, 0, 0);
        }
#pragma unroll
        for (int r = 0; r < 4; ++r)
            glds[(mi * 16 + q * 4 + r) * 36 + ni * 16 + col] = gacc[r];
    }
    __syncthreads();

    // ---- P4: wave 0 does ALL routing on the 32x32 Gram matrix ----
    float cval = 0.f, scale = 0.f, rn = 0.f;
    if (w == 0) {
        // rn_n = 1/||x_n|| from diag(G); matches 1/max(sqrt(nsq),1e-12) for nsq>=1e-24
        float dv = glds[n0 * 36 + n0];
        rn = rsqrtf(fmaxf(dv, 1e-24f));

        // G_u row n0 into registers: g[j] = rn_n * rn_j * G[n][j]
        float g[32];
#pragma unroll
        for (int j8 = 0; j8 < 8; ++j8) {
            f32x4 gv = *reinterpret_cast<const f32x4*>(&glds[n0 * 36 + j8 * 4]);
#pragma unroll
            for (int r = 0; r < 4; ++r) g[j8 * 4 + r] = gv[r] * rn;
        }
#pragma unroll
        for (int j = 0; j < 32; ++j) g[j] *= rdlane(rn, j);

        // 3 routing iterations entirely in-register:
        //   c = 32*softmax(b);  t = G_u c;  sq = c.t (=||s||^2);  b += scale*t
        for (int it = 0; it < 3; ++it) {
            float mx = bval;
            mx = fmaxf(mx, __shfl_xor(mx, 1));  mx = fmaxf(mx, __shfl_xor(mx, 2));
            mx = fmaxf(mx, __shfl_xor(mx, 4));  mx = fmaxf(mx, __shfl_xor(mx, 8));
            mx = fmaxf(mx, __shfl_xor(mx, 16));
            float ex = __expf(bval - mx);
            float sm = red32(ex);
            cval = ex * (32.0f / sm);
            float t0 = 0.f, t1 = 0.f;
#pragma unroll
            for (int j = 0; j < 32; j += 2) {
                t0 = fmaf(g[j],     rdlane(cval, j),     t0);
                t1 = fmaf(g[j + 1], rdlane(cval, j + 1), t1);
            }
            float t = t0 + t1;
            float sq = red32(cval * t);
            scale = sq / ((1.0f + sq) * sqrtf(sq + 1e-9f));
            if (it < 2) bval = fmaf(scale, t, bval);   // agree_n = scale * (G_u c)_n
        }

        if (l < 32) {
            cpls[l] = cval * rn;                                   // c'_n = c_n * rn_n
            out[(size_t)B_ * DOUT_ + (size_t)b * N_ + l] = cval;   // c_out
        }
        if (l == 0) *scls = scale;
    }
    __syncthreads();

    // ---- P6: s_o = sum_n c'_n * x[n][o]; v = scale * s; store poses ----
    {
        float sc = *scls;
        float cv[2][4];
#pragma unroll
        for (int mt = 0; mt < 2; ++mt)
#pragma unroll
            for (int r = 0; r < 4; ++r) cv[mt][r] = cpls[mt * 16 + q * 4 + r];
#pragma unroll
        for (int t = 0; t < 4; ++t) {
            float s = 0.f;
#pragma unroll
            for (int mt = 0; mt < 2; ++mt)
#pragma unroll
                for (int r = 0; r < 4; ++r) s = fmaf(cv[mt][r], acc[mt][t][r], s);
            s += __shfl_xor(s, 16);
            s += __shfl_xor(s, 32);
            if (l < 16) out[(size_t)b * DOUT_ + w * 64 + t * 16 + l] = sc * s;
        }
    }
}

extern "C" void kernel_launch(void* const* d_in, const int* in_sizes, int n_in,
                              void* d_out, int out_size, void* d_ws, size_t ws_size,
                              hipStream_t stream) {
    const float* embeds  = (const float*)d_in[0];
    const float* weights = (const float*)d_in[1];
    const float* W       = (const float*)d_in[2];
    const float* bias    = (const float*)d_in[3];
    float* out = (float*)d_out;
    f16* wp = (f16*)d_ws;    // 64 KB of packed fp16 W

    prep_w<<<16, 256, 0, stream>>>(W, wp);
    dyr_main<<<B_, 256, 0, stream>>>(embeds, weights, wp, bias, out);
}